// Round 6
// baseline (1979.929 us; speedup 1.0000x reference)
//
#include <hip/hip_runtime.h>
#include <cstdint>
#include <cstddef>

#define NN 20000
#define NE 600000

typedef unsigned short u16;
typedef unsigned int   u32;
typedef __bf16 bf16x8 __attribute__((ext_vector_type(8)));
typedef float  f32x4  __attribute__((ext_vector_type(4)));

// ---------------- packed-weight element offsets (bf16 elems) ----------------
constexpr int PK_BB1 = 0;
constexpr int PK_BB2 = PK_BB1 + 384 * 128;
constexpr int PK_WV1 = PK_BB2 + 128 * 128;
constexpr int PK_WV2 = PK_WV1 + 256 * 128;
constexpr int PK_WV3 = PK_WV2 + 128 * 128;
constexpr int PK_WO  = PK_WV3 + 128 * 128;
constexpr int PK_D1  = PK_WO  + 128 * 128;
constexpr int PK_D2  = PK_D1  + 128 * 512;
constexpr int PK_E1  = PK_D2  + 512 * 128;
constexpr int PK_E2  = PK_E1  + 384 * 128;
constexpr int PK_E3  = PK_E2  + 128 * 128;
constexpr int PK_BB3 = PK_E3  + 128 * 128;   // bb3 padded 128x16 (cols>=4 zero)

// ---------------- workspace byte offsets ----------------
constexpr size_t WS_PW    = 0;                       // packed weights (bf16, ~725KB)
constexpr size_t WS_STATS = 0x100000;                // 768 floats stats + flag at +3072
constexpr size_t WS_FLAG  = WS_STATS + 3072;
constexpr size_t WS_HIST  = WS_STATS + 0x1000;       // NN ints
constexpr size_t WS_OFFS  = WS_HIST + 0x14000;       // NN+1 ints
constexpr size_t WS_CNT   = WS_OFFS + 0x14000;       // NN ints
constexpr size_t WS_EIDS  = WS_CNT + 0x14000;        // NE ints
constexpr size_t WS_WLOG  = WS_EIDS + 0x250000;      // NE*4 floats
constexpr size_t WS_AGG   = WS_WLOG + 0x930000;      // NN*128 floats
constexpr size_t WS_R     = WS_AGG + 0xA00000;       // NN*128 floats

// ---------------- helpers ----------------
__device__ __forceinline__ float bf2f(u16 u) {
    return __builtin_bit_cast(float, (u32)u << 16);
}
// native bf16 convert (RTNE, single v_cvt; compiler packs pairs)
__device__ __forceinline__ u16 f2bf(float f) {
    return __builtin_bit_cast(u16, static_cast<__bf16>(f));
}
// fast exact-GELU: erf via A&S 7.1.26 (max abs err 1.5e-7); fast rcp replaces slow f32 div
__device__ __forceinline__ float gelu_f(float x) {
    float z = fabsf(x) * 0.70710678118654752f;
    float t = __builtin_amdgcn_rcpf(fmaf(0.3275911f, z, 1.0f));
    float p = t * fmaf(t, fmaf(t, fmaf(t, fmaf(t, 1.061405429f, -1.453152027f),
                                       1.421413741f), -0.284496736f), 0.254829592f);
    float erfz = fmaf(-p, __expf(-z * z), 1.0f);   // erf(|z|)
    float u = 0.5f * x;
    return fmaf(copysignf(erfz, x), u, u);         // 0.5*x*(1+erf(x/sqrt2))
}
// dtype-flexible scalar load: m!=0 -> f32 data, else bf16 data
__device__ __forceinline__ float ldv(const void* p, size_t i, int m) {
    return m ? ((const float*)p)[i] : bf2f(((const u16*)p)[i]);
}
#define MFMA(a, b, c) __builtin_amdgcn_mfma_f32_16x16x32_bf16(a, b, c, 0, 0, 0)

#define TM 32            // node tile rows per block (k_wo / k_ffn)
#define ET 64            // edge tile rows per block (k_edge1 / k_edge2)
#define XS 136           // LDS row stride (elems): 128 + 8 pad

// MFMA over one 128-wide input chunk from LDS (32 rows: k_wo/k_ffn path)
__device__ __forceinline__ void mma128(const u16* __restrict__ xl, const u16* __restrict__ wp,
                                       int kcBase, int nDiv16, int wave, int lane,
                                       f32x4 acc[2][2]) {
#pragma unroll
    for (int kc = 0; kc < 4; ++kc) {
        int koff = kc * 32 + (lane >> 4) * 8;
        bf16x8 a0 = *(const bf16x8*)&xl[((lane & 15)) * XS + koff];
        bf16x8 a1 = *(const bf16x8*)&xl[((lane & 15) + 16) * XS + koff];
#pragma unroll
        for (int ni = 0; ni < 2; ++ni) {
            int nc = wave * 2 + ni;
            bf16x8 b = *(const bf16x8*)&wp[(((size_t)(kcBase + kc) * nDiv16 + nc) * 64 + lane) * 8];
            acc[0][ni] = MFMA(a0, b, acc[0][ni]);
            acc[1][ni] = MFMA(a1, b, acc[1][ni]);
        }
    }
}

// MFMA over one 128-wide input chunk, 64 rows (edge kernels)
__device__ __forceinline__ void mma64r(const u16* __restrict__ xl, const u16* __restrict__ wp,
                                       int kcBase, int wave, int lane, f32x4 acc[4][2]) {
#pragma unroll
    for (int kc = 0; kc < 4; ++kc) {
        int koff = kc * 32 + (lane >> 4) * 8;
        bf16x8 a[4];
#pragma unroll
        for (int mi = 0; mi < 4; ++mi)
            a[mi] = *(const bf16x8*)&xl[((lane & 15) + 16 * mi) * XS + koff];
#pragma unroll
        for (int ni = 0; ni < 2; ++ni) {
            int nc = wave * 2 + ni;
            bf16x8 b = *(const bf16x8*)&wp[(((size_t)(kcBase + kc) * 8 + nc) * 64 + lane) * 8];
#pragma unroll
            for (int mi = 0; mi < 4; ++mi)
                acc[mi][ni] = MFMA(a[mi], b, acc[mi][ni]);
        }
    }
}

__device__ __forceinline__ void epi_lds(f32x4 acc[2][2], u16* hl, const void* biasG,
                                        int wave, int lane, bool doGelu, int f32m) {
    int col0 = wave * 32;
#pragma unroll
    for (int ni = 0; ni < 2; ++ni) {
        int col = col0 + ni * 16 + (lane & 15);
        float b = ldv(biasG, col, f32m);
#pragma unroll
        for (int mi = 0; mi < 2; ++mi) {
            int rb = mi * 16 + (lane >> 4) * 4;
#pragma unroll
            for (int r = 0; r < 4; ++r) {
                float v = acc[mi][ni][r] + b;
                if (doGelu) v = gelu_f(v);
                hl[(rb + r) * XS + col] = f2bf(v);
            }
        }
    }
}

// 64-row epilogue (edge kernels)
__device__ __forceinline__ void epi64(f32x4 acc[4][2], u16* hl, const void* biasG,
                                      int wave, int lane, int f32m) {
    int col0 = wave * 32;
#pragma unroll
    for (int ni = 0; ni < 2; ++ni) {
        int col = col0 + ni * 16 + (lane & 15);
        float b = ldv(biasG, col, f32m);
#pragma unroll
        for (int mi = 0; mi < 4; ++mi) {
            int rb = mi * 16 + (lane >> 4) * 4;
#pragma unroll
            for (int r = 0; r < 4; ++r)
                hl[(rb + r) * XS + col] = f2bf(gelu_f(acc[mi][ni][r] + b));
        }
    }
}

// stage 8 contiguous elems (col c8*8) of row `row` of a 128-wide table into LDS
__device__ __forceinline__ void stage_row8(u16* dst8, const void* table, size_t row, int c8, int f32m) {
    if (f32m) {
        const float* s = (const float*)table + row * 128 + c8 * 8;
        float4 v0 = *(const float4*)s;
        float4 v1 = *(const float4*)(s + 4);
        uint4 o;
        o.x = (u32)f2bf(v0.x) | ((u32)f2bf(v0.y) << 16);
        o.y = (u32)f2bf(v0.z) | ((u32)f2bf(v0.w) << 16);
        o.z = (u32)f2bf(v1.x) | ((u32)f2bf(v1.y) << 16);
        o.w = (u32)f2bf(v1.z) | ((u32)f2bf(v1.w) << 16);
        *(uint4*)dst8 = o;
    } else {
        *(uint4*)dst8 = *(const uint4*)((const u16*)table + row * 128 + c8 * 8);
    }
}

// 64-row staging (edge kernels): thread covers rows r0, r0+16, r0+32, r0+48
__device__ __forceinline__ void stage_gidx64(u16* dst, const void* table, const int* gIdx,
                                             int tid, int f32m) {
    int r0 = tid >> 4, c = tid & 15;
#pragma unroll
    for (int p = 0; p < 4; ++p) {
        int r = r0 + p * 16;
        stage_row8(&dst[r * XS + c * 8], table, (size_t)gIdx[r], c, f32m);
    }
}
__device__ __forceinline__ void stage_seq64(u16* dst, const void* table, size_t rowBase,
                                            int tid, int f32m) {
    int r0 = tid >> 4, c = tid & 15;
#pragma unroll
    for (int p = 0; p < 4; ++p) {
        int r = r0 + p * 16;
        stage_row8(&dst[r * XS + c * 8], table, rowBase + r, c, f32m);
    }
}

// ---------------- dtype detector ----------------
__global__ void k_detect(const void* hV, int* flag) {
    int l = threadIdx.x;
    const u16* p = (const u16*)hV;
    float m = fmaxf(fabsf(bf2f(p[l])), fabsf(bf2f(p[64 + l])));
    for (int s = 1; s < 64; s <<= 1) m = fmaxf(m, __shfl_xor(m, s));
    if (l == 0) *flag = (m > 1e4f) ? 1 : 0;
}

// ---------------- kernel: pack weights into B-fragment order ----------------
__global__ void k_pack(const void* bb1, const void* bb2, const void* wv1, const void* wv2,
                       const void* wv3, const void* wo, const void* d1, const void* d2,
                       const void* e1, const void* e2, const void* e3, const void* bb3,
                       u16* pw, const int* dflag) {
    int f32m = *dflag;
    const int Ks[12] = {384, 128, 256, 128, 128, 128, 128, 512, 384, 128, 128, 128};
    const int Ns[12] = {128, 128, 128, 128, 128, 128, 512, 128, 128, 128, 128, 16};
    const void* srcs[12] = {bb1, bb2, wv1, wv2, wv3, wo, d1, d2, e1, e2, e3, bb3};
    int gid = blockIdx.x * 256 + threadIdx.x;
    int lane = gid & 63;
    int fid = gid >> 6;
    if (fid >= 708) return;
    int w = 0, base = 0, dstoff = 0;
    for (int i = 0; i < 12; ++i) {
        int nf = (Ks[i] / 32) * (Ns[i] / 16);
        if (fid < base + nf) { w = i; break; }
        base += nf;
        dstoff += Ks[i] * Ns[i];
    }
    int f = fid - base;
    int N = Ns[w];
    int kc = f / (N / 16), nc = f % (N / 16);
    const void* S = srcs[w];
    u16* D = pw + dstoff + ((size_t)f * 64 + lane) * 8;
    int krow = kc * 32 + (lane >> 4) * 8;
    int col = nc * 16 + (lane & 15);
#pragma unroll
    for (int j = 0; j < 8; ++j) {
        float v;
        if (w == 11) v = (col < 4) ? ldv(S, (size_t)(krow + j) * 4 + col, f32m) : 0.f;
        else         v = ldv(S, (size_t)(krow + j) * N + col, f32m);
        D[j] = f2bf(v);
    }
}

// ---------------- CSR build ----------------
__global__ void k_hist(const int* src, int* hist) {
    int e = blockIdx.x * 256 + threadIdx.x;
    if (e < NE) atomicAdd(&hist[src[e]], 1);
}

__global__ void k_scan(const int* hist, int* offs, int* cnt) {
    __shared__ int buf[1024];
    __shared__ int carry;
    if (threadIdx.x == 0) carry = 0;
    __syncthreads();
    for (int b = 0; b < NN; b += 1024) {
        int i = b + threadIdx.x;
        int v = (i < NN) ? hist[i] : 0;
        buf[threadIdx.x] = v;
        __syncthreads();
        for (int s = 1; s < 1024; s <<= 1) {
            int t = (threadIdx.x >= s) ? buf[threadIdx.x - s] : 0;
            __syncthreads();
            buf[threadIdx.x] += t;
            __syncthreads();
        }
        int excl = buf[threadIdx.x] - v + carry;
        if (i < NN) { offs[i] = excl; cnt[i] = excl; }
        __syncthreads();
        if (threadIdx.x == 1023) carry += buf[1023];
        __syncthreads();
    }
    if (threadIdx.x == 0) offs[NN] = carry;
}

__global__ void k_fill(const int* src, int* cnt, int* eids) {
    int e = blockIdx.x * 256 + threadIdx.x;
    if (e < NE) {
        int slot = atomicAdd(&cnt[src[e]], 1);
        eids[slot] = e;
    }
}

// ---------------- kernel: fused bias-MLP + value-MLP over edges (64 rows/block) ----------------
__global__ __launch_bounds__(256, 2) void k_edge1(
    const void* __restrict__ hV, const void* __restrict__ hE, const int* __restrict__ eidx,
    const u16* __restrict__ pw, const void* bb1b, const void* bb2b,
    const void* bb3b, const void* wv1b, const void* wv2b, const void* wv3b,
    float* __restrict__ wlog, void* __restrict__ dout, const int* dflag) {
    __shared__ __attribute__((aligned(16))) u16 X[ET * XS];
    __shared__ __attribute__((aligned(16))) u16 Y[ET * XS];
    __shared__ __attribute__((aligned(16))) u16 Z[ET * XS];
    int f32m = *dflag;
    int tid = threadIdx.x, wave = tid >> 6, lane = tid & 63;
    long e0 = (long)blockIdx.x * ET;

    // P1: stage all three chunks concurrently
    stage_gidx64(X, hV, eidx + e0, tid, f32m);        // hV[src]
    stage_seq64 (Y, hE, (size_t)e0, tid, f32m);       // hE
    stage_gidx64(Z, hV, eidx + NE + e0, tid, f32m);   // hV[dst]
    __syncthreads();
    // P2: layer-1 MFMAs, all chunks back-to-back
    f32x4 accB[4][2] = {};
    f32x4 accV[4][2] = {};
    mma64r(X, pw + PK_BB1, 0, wave, lane, accB);
    mma64r(Y, pw + PK_BB1, 4, wave, lane, accB);
    mma64r(Z, pw + PK_BB1, 8, wave, lane, accB);
    mma64r(Y, pw + PK_WV1, 0, wave, lane, accV);
    mma64r(Z, pw + PK_WV1, 4, wave, lane, accV);
    __syncthreads();
    // P3: epilogues into freed buffers
    epi64(accB, X, bb1b, wave, lane, f32m);   // h1b -> X
    epi64(accV, Y, wv1b, wave, lane, f32m);   // h1v -> Y
    __syncthreads();
    // P4: layer-2 MFMAs
    f32x4 accB2[4][2] = {};
    f32x4 accV2[4][2] = {};
    mma64r(X, pw + PK_BB2, 0, wave, lane, accB2);
    mma64r(Y, pw + PK_WV2, 0, wave, lane, accV2);
    __syncthreads();
    // P5: epilogues
    epi64(accB2, Z, bb2b, wave, lane, f32m);  // h2b -> Z
    epi64(accV2, X, wv2b, wave, lane, f32m);  // h2v -> X
    __syncthreads();
    // P6: l3 value (WV3 on X) -> Vout; l3 bias (BB3 on Z, wave 0) -> wlog
    u16* Vout = (u16*)((char*)dout + (size_t)NN * 128 * (f32m ? 4 : 2));
    f32x4 accV3[4][2] = {};
    mma64r(X, pw + PK_WV3, 0, wave, lane, accV3);
    {
        int col0 = wave * 32;
#pragma unroll
        for (int ni = 0; ni < 2; ++ni) {
            int col = col0 + ni * 16 + (lane & 15);
            float b = ldv(wv3b, col, f32m);
#pragma unroll
            for (int mi = 0; mi < 4; ++mi) {
                int rb = mi * 16 + (lane >> 4) * 4;
#pragma unroll
                for (int r = 0; r < 4; ++r) {
                    long row = e0 + rb + r;
                    Vout[row * 128 + col] = f2bf(accV3[mi][ni][r] + b);
                }
            }
        }
    }
    if (wave == 0) {
        f32x4 aw[4] = {};
#pragma unroll
        for (int kc = 0; kc < 4; ++kc) {
            int koff = kc * 32 + (lane >> 4) * 8;
            bf16x8 b = *(const bf16x8*)&pw[PK_BB3 + ((size_t)kc * 64 + lane) * 8];
#pragma unroll
            for (int mi = 0; mi < 4; ++mi) {
                bf16x8 a = *(const bf16x8*)&Z[((lane & 15) + 16 * mi) * XS + koff];
                aw[mi] = MFMA(a, b, aw[mi]);
            }
        }
        if ((lane & 15) < 4) {
            int col = lane & 15;
            int rbase = (lane >> 4) * 4;
            float b3 = ldv(bb3b, col, f32m);
#pragma unroll
            for (int mi = 0; mi < 4; ++mi)
#pragma unroll
                for (int r = 0; r < 4; ++r)
                    wlog[(e0 + mi * 16 + rbase + r) * 4 + col] = aw[mi][r] + b3;
        }
    }
}

// ---------------- kernel: per-node scatter-softmax + weighted segment sum ----------------
__global__ void k_agg(const int* __restrict__ offs, const int* __restrict__ eids,
                      const float* __restrict__ wlog, const void* __restrict__ dout,
                      float* __restrict__ agg, const int* dflag) {
    int f32m = *dflag;
    const u16* V = (const u16*)((const char*)dout + (size_t)NN * 128 * (f32m ? 4 : 2));
    int node = blockIdx.x;
    int l = threadIdx.x;   // 0..63
    int beg = offs[node], end = offs[node + 1];
    int deg = end - beg;
    if (deg == 0) {
        agg[(size_t)node * 128 + 2 * l] = 0.f;
        agg[(size_t)node * 128 + 2 * l + 1] = 0.f;
        return;
    }
    int h = l & 3;
    float lmax = -3.0e38f;
    for (int i = (l >> 2); i < deg; i += 16) {
        int e = eids[beg + i];
        lmax = fmaxf(lmax, wlog[(size_t)e * 4 + h]);
    }
    for (int s = 4; s < 64; s <<= 1) lmax = fmaxf(lmax, __shfl_xor(lmax, s));
    float lsum = 0.f;
    for (int i = (l >> 2); i < deg; i += 16) {
        int e = eids[beg + i];
        lsum += __expf(wlog[(size_t)e * 4 + h] - lmax);
    }
    for (int s = 4; s < 64; s <<= 1) lsum += __shfl_xor(lsum, s);
    int hh = l >> 4;                // head of cols (2l, 2l+1)
    float mh = __shfl(lmax, hh);
    float inv = __builtin_amdgcn_rcpf(__shfl(lsum, hh));
    float a0 = 0.f, a1 = 0.f;
    for (int i = 0; i < deg; ++i) {
        int e = eids[beg + i];
        float aw = __expf(wlog[(size_t)e * 4 + hh] - mh) * inv;
        u32 vv = *(const u32*)&V[(size_t)e * 128 + 2 * l];
        a0 += aw * bf2f((u16)(vv & 0xffffu));
        a1 += aw * bf2f((u16)(vv >> 16));
    }
    float2 o;
    o.x = a0;
    o.y = a1;
    *(float2*)&agg[(size_t)node * 128 + 2 * l] = o;
}

// ---------------- kernel: dh = agg @ wo ; r0 = hV + dh ; BN0 stats ----------------
__global__ __launch_bounds__(256, 2) void k_wo(const float* __restrict__ agg,
                                               const void* __restrict__ hV,
                                               const u16* __restrict__ pw,
                                               float* __restrict__ rbuf,
                                               float* __restrict__ stats0, const int* dflag) {
    __shared__ __attribute__((aligned(16))) u16 xb[TM * XS];
    __shared__ float lsum[128], lsq[128];
    int f32m = *dflag;
    int tid = threadIdx.x, wave = tid >> 6, lane = tid & 63;
    long n0 = (long)blockIdx.x * TM;
    if (tid < 128) { lsum[tid] = 0.f; lsq[tid] = 0.f; }
    {
        int r = tid >> 3, cc = (tid & 7) * 16;
        long row = n0 + r;
        for (int j = 0; j < 16; j += 4) {
            float4 v = {0.f, 0.f, 0.f, 0.f};
            if (row < NN) v = *(const float4*)&agg[row * 128 + cc + j];
            u16* d = &xb[r * XS + cc + j];
            d[0] = f2bf(v.x); d[1] = f2bf(v.y); d[2] = f2bf(v.z); d[3] = f2bf(v.w);
        }
    }
    __syncthreads();
    f32x4 acc[2][2] = {};
    mma128(xb, pw + PK_WO, 0, 8, wave, lane, acc);
    int col0 = wave * 32;
#pragma unroll
    for (int ni = 0; ni < 2; ++ni) {
        int col = col0 + ni * 16 + (lane & 15);
#pragma unroll
        for (int mi = 0; mi < 2; ++mi) {
            int rb = mi * 16 + (lane >> 4) * 4;
#pragma unroll
            for (int r = 0; r < 4; ++r) {
                long row = n0 + rb + r;
                if (row < NN) {
                    float v = ldv(hV, (size_t)row * 128 + col, f32m) + acc[mi][ni][r];
                    rbuf[row * 128 + col] = v;
                    atomicAdd(&lsum[col], v);
                    atomicAdd(&lsq[col], v * v);
                }
            }
        }
    }
    __syncthreads();
    if (tid < 128) {
        atomicAdd(&stats0[tid], lsum[tid]);
        atomicAdd(&stats0[128 + tid], lsq[tid]);
    }
}

// ---------------- kernel: BN0 apply + FFN + residual + BN1 stats ----------------
__global__ __launch_bounds__(256, 2) void k_ffn(float* __restrict__ rbuf,
                                                const float* __restrict__ stats0,
                                                const void* n0g, const void* n0b,
                                                const u16* __restrict__ pw,
                                                const void* d1b, const void* d2b,
                                                float* __restrict__ stats1, const int* dflag) {
    __shared__ float bnS[128], bnB[128];
    __shared__ float h1f[TM * 128];
    __shared__ __attribute__((aligned(16))) u16 h1x[TM * XS];
    __shared__ __attribute__((aligned(16))) u16 hid[TM * 520];
    __shared__ float lsum[128], lsq[128];
    int f32m = *dflag;
    int tid = threadIdx.x, wave = tid >> 6, lane = tid & 63;
    long n0 = (long)blockIdx.x * TM;
    if (tid < 128) {
        float m = stats0[tid] * (1.f / NN);
        float v = stats0[128 + tid] * (1.f / NN) - m * m;
        float s = ldv(n0g, tid, f32m) * rsqrtf(v + 1e-5f);
        bnS[tid] = s;
        bnB[tid] = ldv(n0b, tid, f32m) - m * s;
        lsum[tid] = 0.f;
        lsq[tid] = 0.f;
    }
    __syncthreads();
    {
        int r = tid >> 3, cc = (tid & 7) * 16;
        long row = n0 + r;
        for (int j = 0; j < 16; ++j) {
            int c = cc + j;
            float v = (row < NN) ? (rbuf[row * 128 + c] * bnS[c] + bnB[c]) : 0.f;
            h1f[r * 128 + c] = v;
            h1x[r * XS + c] = f2bf(v);
        }
    }
    __syncthreads();
    // GEMM1: (32 x 128) @ (128 x 512)
    f32x4 acc1[2][8] = {};
#pragma unroll
    for (int kc = 0; kc < 4; ++kc) {
        int koff = kc * 32 + (lane >> 4) * 8;
        bf16x8 a0 = *(const bf16x8*)&h1x[(lane & 15) * XS + koff];
        bf16x8 a1 = *(const bf16x8*)&h1x[((lane & 15) + 16) * XS + koff];
#pragma unroll
        for (int ni = 0; ni < 8; ++ni) {
            int nc = wave * 8 + ni;
            bf16x8 b = *(const bf16x8*)&pw[PK_D1 + (((size_t)kc * 32 + nc) * 64 + lane) * 8];
            acc1[0][ni] = MFMA(a0, b, acc1[0][ni]);
            acc1[1][ni] = MFMA(a1, b, acc1[1][ni]);
        }
    }
#pragma unroll
    for (int ni = 0; ni < 8; ++ni) {
        int col = wave * 128 + ni * 16 + (lane & 15);
        float bb = ldv(d1b, col, f32m);
#pragma unroll
        for (int mi = 0; mi < 2; ++mi) {
            int rb = mi * 16 + (lane >> 4) * 4;
#pragma unroll
            for (int r = 0; r < 4; ++r)
                hid[(rb + r) * 520 + col] = f2bf(gelu_f(acc1[mi][ni][r] + bb));
        }
    }
    __syncthreads();
    // GEMM2: (32 x 512) @ (512 x 128)
    f32x4 acc2[2][2] = {};
#pragma unroll
    for (int kc = 0; kc < 16; ++kc) {
        int koff = kc * 32 + (lane >> 4) * 8;
        bf16x8 a0 = *(const bf16x8*)&hid[(lane & 15) * 520 + koff];
        bf16x8 a1 = *(const bf16x8*)&hid[((lane & 15) + 16) * 520 + koff];
#pragma unroll
        for (int ni = 0; ni < 2; ++ni) {
            int nc = wave * 2 + ni;
            bf16x8 b = *(const bf16x8*)&pw[PK_D2 + (((size_t)kc * 8 + nc) * 64 + lane) * 8];
            acc2[0][ni] = MFMA(a0, b, acc2[0][ni]);
            acc2[1][ni] = MFMA(a1, b, acc2[1][ni]);
        }
    }
    int col0 = wave * 32;
#pragma unroll
    for (int ni = 0; ni < 2; ++ni) {
        int col = col0 + ni * 16 + (lane & 15);
        float db = ldv(d2b, col, f32m);
#pragma unroll
        for (int mi = 0; mi < 2; ++mi) {
            int rb = mi * 16 + (lane >> 4) * 4;
#pragma unroll
            for (int r = 0; r < 4; ++r) {
                long row = n0 + rb + r;
                if (row < NN) {
                    float v = h1f[(rb + r) * 128 + col] + acc2[mi][ni][r] + db;
                    rbuf[row * 128 + col] = v;
                    atomicAdd(&lsum[col], v);
                    atomicAdd(&lsq[col], v * v);
                }
            }
        }
    }
    __syncthreads();
    if (tid < 128) {
        atomicAdd(&stats1[tid], lsum[tid]);
        atomicAdd(&stats1[128 + tid], lsq[tid]);
    }
}

// ---------------- kernel: BN1 normalize -> h_V output ----------------
__global__ void k_out_hV(const float* __restrict__ rbuf, const float* __restrict__ stats1,
                         const void* n1g, const void* n1b, void* __restrict__ dout,
                         const int* dflag) {
    int f32m = *dflag;
    int idx = blockIdx.x * 256 + threadIdx.x;
    if (idx >= NN * 128) return;
    int c = idx & 127;
    float m = stats1[c] * (1.f / NN);
    float v = stats1[128 + c] * (1.f / NN) - m * m;
    float s = ldv(n1g, c, f32m) * rsqrtf(v + 1e-5f);
    float b = ldv(n1b, c, f32m) - m * s;
    float o = rbuf[idx] * s + b;
    if (f32m) ((float*)dout)[idx] = o;
    else      ((u16*)dout)[idx] = f2bf(o);
}

// ---------------- kernel: edge MLP + residual + edge-BN stats (64 rows/block) ----------------
__global__ __launch_bounds__(256, 2) void k_edge2(
    const void* __restrict__ hE, const int* __restrict__ eidx,
    const u16* __restrict__ pw, const void* e1b, const void* e2b, const void* e3b,
    void* __restrict__ dout, float* __restrict__ statsE, const int* dflag) {
    __shared__ __attribute__((aligned(16))) u16 X[ET * XS];
    __shared__ __attribute__((aligned(16))) u16 Y[ET * XS];
    __shared__ __attribute__((aligned(16))) u16 Z[ET * XS];
    int f32m = *dflag;
    int tid = threadIdx.x, wave = tid >> 6, lane = tid & 63;
    long e0 = (long)blockIdx.x * ET;
    const void* hV2 = dout;   // updated h_V (elem type per flag)

    // P1: stage all three chunks concurrently
    stage_gidx64(X, hV2, eidx + e0, tid, f32m);        // hV2[src]
    stage_seq64 (Z, hE, (size_t)e0, tid, f32m);        // hE
    stage_gidx64(Y, hV2, eidx + NE + e0, tid, f32m);   // hV2[dst]
    // preload residual hE values for the epilogue (latency hides under the MLP)
    int col0 = wave * 32, rbase = (lane >> 4) * 4, cl = lane & 15;
    float res[2][4][4];
#pragma unroll
    for (int ni = 0; ni < 2; ++ni)
#pragma unroll
        for (int mi = 0; mi < 4; ++mi)
#pragma unroll
            for (int r = 0; r < 4; ++r)
                res[ni][mi][r] = ldv(hE, (size_t)(e0 + mi * 16 + rbase + r) * 128
                                              + col0 + ni * 16 + cl, f32m);
    __syncthreads();
    // P2: E1 over all three chunks
    f32x4 a1[4][2] = {};
    mma64r(X, pw + PK_E1, 0, wave, lane, a1);     // hV2[src]
    mma64r(Z, pw + PK_E1, 4, wave, lane, a1);     // hE
    mma64r(Y, pw + PK_E1, 8, wave, lane, a1);     // hV2[dst]
    __syncthreads();
    // P3: epi -> X
    epi64(a1, X, e1b, wave, lane, f32m);          // h1 -> X
    __syncthreads();
    // P4: E2 + epi -> Y (Y has no live readers; no barrier between mma and epi)
    f32x4 a2[4][2] = {};
    mma64r(X, pw + PK_E2, 0, wave, lane, a2);
    epi64(a2, Y, e2b, wave, lane, f32m);          // h2 -> Y
    __syncthreads();
    // P5: E3 + epilogue (residual from preloaded regs)
    f32x4 a3[4][2] = {};
    mma64r(Y, pw + PK_E3, 0, wave, lane, a3);
    float* yb32 = (float*)((char*)dout + (size_t)NN * 512);
    u16*   yb16 = (u16*)((char*)dout + (size_t)NN * 256);
    float ssum[2] = {0.f, 0.f}, ssq[2] = {0.f, 0.f};
#pragma unroll
    for (int ni = 0; ni < 2; ++ni) {
        int col = col0 + ni * 16 + cl;
        float b = ldv(e3b, col, f32m);
#pragma unroll
        for (int mi = 0; mi < 4; ++mi) {
            int rb = mi * 16 + rbase;
#pragma unroll
            for (int r = 0; r < 4; ++r) {
                long row = e0 + rb + r;
                float y = res[ni][mi][r] + a3[mi][ni][r] + b;
                if (f32m) yb32[row * 128 + col] = y;
                else      yb16[row * 128 + col] = f2bf(y);
                ssum[ni] += y;
                ssq[ni] += y * y;
            }
        }
    }
    // lanes {c, c+16, c+32, c+48} together cover all 64 rows of column col0+ni*16+c
#pragma unroll
    for (int ni = 0; ni < 2; ++ni) {
        ssum[ni] += __shfl_xor(ssum[ni], 16);
        ssum[ni] += __shfl_xor(ssum[ni], 32);
        ssq[ni]  += __shfl_xor(ssq[ni], 16);
        ssq[ni]  += __shfl_xor(ssq[ni], 32);
    }
    if (lane < 16) {
#pragma unroll
        for (int ni = 0; ni < 2; ++ni) {
            int col = col0 + ni * 16 + lane;
            atomicAdd(&statsE[col], ssum[ni]);
            atomicAdd(&statsE[128 + col], ssq[ni]);
        }
    }
}

// ---------------- kernel: edge BN normalize in place -> h_E output (vec4) ----------------
__global__ void k_out_hE(const float* __restrict__ statsE, const void* eng, const void* enb,
                         void* __restrict__ dout, const int* dflag) {
    int f32m = *dflag;
    long i4 = (long)blockIdx.x * 256 + threadIdx.x;   // 4-elem group
    if (i4 >= (long)NE * 32) return;
    int c0 = (int)((i4 & 31) * 4);
    float s[4], b[4];
#pragma unroll
    for (int j = 0; j < 4; ++j) {
        int c = c0 + j;
        float m = statsE[c] * (1.f / NE);
        float v = statsE[128 + c] * (1.f / NE) - m * m;
        float sc = ldv(eng, c, f32m) * rsqrtf(v + 1e-5f);
        s[j] = sc;
        b[j] = ldv(enb, c, f32m) - m * sc;
    }
    if (f32m) {
        float4* y = (float4*)((char*)dout + (size_t)NN * 512);
        float4 v = y[i4];
        v.x = v.x * s[0] + b[0];
        v.y = v.y * s[1] + b[1];
        v.z = v.z * s[2] + b[2];
        v.w = v.w * s[3] + b[3];
        y[i4] = v;
    } else {
        ushort4* y = (ushort4*)((char*)dout + (size_t)NN * 256);
        ushort4 v = y[i4];
        v.x = f2bf(bf2f(v.x) * s[0] + b[0]);
        v.y = f2bf(bf2f(v.y) * s[1] + b[1]);
        v.z = f2bf(bf2f(v.z) * s[2] + b[2]);
        v.w = f2bf(bf2f(v.w) * s[3] + b[3]);
        y[i4] = v;
    }
}

// ---------------- launch ----------------
extern "C" void kernel_launch(void* const* d_in, const int* in_sizes, int n_in,
                              void* d_out, int out_size, void* d_ws, size_t ws_size,
                              hipStream_t stream) {
    (void)in_sizes; (void)n_in; (void)out_size; (void)ws_size;
    const void* hV = d_in[0];
    const void* hE = d_in[1];
    const int* eidx = (const int*)d_in[2];
    // d_in[3] batch_id unused (context is identity)
    const void* wv1w = d_in[4];  const void* wv1b = d_in[5];
    const void* wv2w = d_in[6];  const void* wv2b = d_in[7];
    const void* wv3w = d_in[8];  const void* wv3b = d_in[9];
    const void* bb1w = d_in[10]; const void* bb1b = d_in[11];
    const void* bb2w = d_in[12]; const void* bb2b = d_in[13];
    const void* bb3w = d_in[14]; const void* bb3b = d_in[15];
    const void* wow  = d_in[16];
    const void* n0g = d_in[17]; const void* n0b = d_in[18];
    const void* n1g = d_in[19]; const void* n1b = d_in[20];
    const void* d1w = d_in[21]; const void* d1b = d_in[22];
    const void* d2w = d_in[23]; const void* d2b = d_in[24];
    const void* e1w = d_in[25]; const void* e1b = d_in[26];
    const void* e2w = d_in[27]; const void* e2b = d_in[28];
    const void* e3w = d_in[29]; const void* e3b = d_in[30];
    const void* eng = d_in[31]; const void* enb = d_in[32];

    char* ws = (char*)d_ws;
    u16* pw      = (u16*)(ws + WS_PW);
    float* stats = (float*)(ws + WS_STATS);   // stats0 | stats1(+256) | statsE(+512)
    int* dflag   = (int*)(ws + WS_FLAG);
    int* hist    = (int*)(ws + WS_HIST);
    int* offs    = (int*)(ws + WS_OFFS);
    int* cnt     = (int*)(ws + WS_CNT);
    int* eids    = (int*)(ws + WS_EIDS);
    float* wlog  = (float*)(ws + WS_WLOG);
    float* agg   = (float*)(ws + WS_AGG);
    float* rbuf  = (float*)(ws + WS_R);

    // zero stats/flag (4KB) + hist (80000B), contiguous
    hipMemsetAsync(ws + WS_STATS, 0, 0x1000 + NN * sizeof(int), stream);

    k_detect<<<1, 64, 0, stream>>>(hV, dflag);
    k_pack<<<177, 256, 0, stream>>>(bb1w, bb2w, wv1w, wv2w, wv3w, wow, d1w, d2w,
                                    e1w, e2w, e3w, bb3w, pw, dflag);
    k_hist<<<(NE + 255) / 256, 256, 0, stream>>>(eidx, hist);
    k_scan<<<1, 1024, 0, stream>>>(hist, offs, cnt);
    k_fill<<<(NE + 255) / 256, 256, 0, stream>>>(eidx, cnt, eids);
    k_edge1<<<NE / ET, 256, 0, stream>>>(hV, hE, eidx, pw, bb1b, bb2b, bb3b,
                                         wv1b, wv2b, wv3b, wlog, d_out, dflag);
    k_agg<<<NN, 64, 0, stream>>>(offs, eids, wlog, d_out, agg, dflag);
    k_wo<<<(NN + TM - 1) / TM, 256, 0, stream>>>(agg, hV, pw, rbuf, stats, dflag);
    k_ffn<<<(NN + TM - 1) / TM, 256, 0, stream>>>(rbuf, stats, n0g, n0b, pw, d1b, d2b,
                                                  stats + 256, dflag);
    k_out_hV<<<(NN * 128 + 255) / 256, 256, 0, stream>>>(rbuf, stats + 256, n1g, n1b, d_out, dflag);
    k_edge2<<<NE / ET, 256, 0, stream>>>(hE, eidx, pw, e1b, e2b, e3b, d_out, stats + 512, dflag);
    k_out_hE<<<(int)(((long)NE * 32 + 255) / 256), 256, 0, stream>>>(stats + 512, eng, enb, d_out, dflag);
}

// Round 7
// 1885.653 us; speedup vs baseline: 1.0500x; 1.0500x over previous
//
#include <hip/hip_runtime.h>
#include <cstdint>
#include <cstddef>

#define NN 20000
#define NE 600000

typedef unsigned short u16;
typedef unsigned int   u32;
typedef __bf16 bf16x8 __attribute__((ext_vector_type(8)));
typedef float  f32x4  __attribute__((ext_vector_type(4)));

// ---------------- packed-weight element offsets (bf16 elems) ----------------
constexpr int PK_BB1 = 0;
constexpr int PK_BB2 = PK_BB1 + 384 * 128;
constexpr int PK_WV1 = PK_BB2 + 128 * 128;
constexpr int PK_WV2 = PK_WV1 + 256 * 128;
constexpr int PK_WV3 = PK_WV2 + 128 * 128;
constexpr int PK_WO  = PK_WV3 + 128 * 128;
constexpr int PK_D1  = PK_WO  + 128 * 128;
constexpr int PK_D2  = PK_D1  + 128 * 512;
constexpr int PK_E1  = PK_D2  + 512 * 128;
constexpr int PK_E2  = PK_E1  + 384 * 128;
constexpr int PK_E3  = PK_E2  + 128 * 128;
constexpr int PK_BB3 = PK_E3  + 128 * 128;   // bb3 padded 128x16 (cols>=4 zero)

// ---------------- workspace byte offsets ----------------
constexpr size_t WS_PW    = 0;                       // packed weights (bf16, ~725KB)
constexpr size_t WS_STATS = 0x100000;                // 768 floats stats + flag at +3072
constexpr size_t WS_FLAG  = WS_STATS + 3072;
constexpr size_t WS_HIST  = WS_STATS + 0x1000;       // NN ints
constexpr size_t WS_OFFS  = WS_HIST + 0x14000;       // NN+1 ints
constexpr size_t WS_CNT   = WS_OFFS + 0x14000;       // NN ints
constexpr size_t WS_EIDS  = WS_CNT + 0x14000;        // NE ints
constexpr size_t WS_WLOG  = WS_EIDS + 0x250000;      // NE*4 floats
constexpr size_t WS_AGG   = WS_WLOG + 0x930000;      // NN*128 floats (also PA / P2a)
constexpr size_t WS_R     = WS_AGG + 0xA00000;       // NN*128 floats (also PC / P2c)
constexpr size_t WS_PV    = WS_R + 0xA00000;         // NN*128 floats (PV, bf16-mode only)

// ---------------- helpers ----------------
__device__ __forceinline__ float bf2f(u16 u) {
    return __builtin_bit_cast(float, (u32)u << 16);
}
__device__ __forceinline__ u16 f2bf(float f) {
    return __builtin_bit_cast(u16, static_cast<__bf16>(f));
}
// fast exact-GELU: erf via A&S 7.1.26 (max abs err 1.5e-7)
__device__ __forceinline__ float gelu_f(float x) {
    float z = fabsf(x) * 0.70710678118654752f;
    float t = __builtin_amdgcn_rcpf(fmaf(0.3275911f, z, 1.0f));
    float p = t * fmaf(t, fmaf(t, fmaf(t, fmaf(t, 1.061405429f, -1.453152027f),
                                       1.421413741f), -0.284496736f), 0.254829592f);
    float erfz = fmaf(-p, __expf(-z * z), 1.0f);   // erf(|z|)
    float u = 0.5f * x;
    return fmaf(copysignf(erfz, x), u, u);         // 0.5*x*(1+erf(x/sqrt2))
}
// dtype-flexible scalar load: m!=0 -> f32 data, else bf16 data
__device__ __forceinline__ float ldv(const void* p, size_t i, int m) {
    return m ? ((const float*)p)[i] : bf2f(((const u16*)p)[i]);
}
#define MFMA(a, b, c) __builtin_amdgcn_mfma_f32_16x16x32_bf16(a, b, c, 0, 0, 0)

#define TM 32            // tile rows per block
#define XS 136           // LDS row stride (elems): 128 + 8 pad

// MFMA over one 128-wide input chunk from LDS (32 rows)
__device__ __forceinline__ void mma128(const u16* __restrict__ xl, const u16* __restrict__ wp,
                                       int kcBase, int nDiv16, int wave, int lane,
                                       f32x4 acc[2][2]) {
#pragma unroll
    for (int kc = 0; kc < 4; ++kc) {
        int koff = kc * 32 + (lane >> 4) * 8;
        bf16x8 a0 = *(const bf16x8*)&xl[((lane & 15)) * XS + koff];
        bf16x8 a1 = *(const bf16x8*)&xl[((lane & 15) + 16) * XS + koff];
#pragma unroll
        for (int ni = 0; ni < 2; ++ni) {
            int nc = wave * 2 + ni;
            bf16x8 b = *(const bf16x8*)&wp[(((size_t)(kcBase + kc) * nDiv16 + nc) * 64 + lane) * 8];
            acc[0][ni] = MFMA(a0, b, acc[0][ni]);
            acc[1][ni] = MFMA(a1, b, acc[1][ni]);
        }
    }
}

__device__ __forceinline__ void epi_lds(f32x4 acc[2][2], u16* hl, const void* biasG,
                                        int wave, int lane, bool doGelu, int f32m) {
    int col0 = wave * 32;
#pragma unroll
    for (int ni = 0; ni < 2; ++ni) {
        int col = col0 + ni * 16 + (lane & 15);
        float b = ldv(biasG, col, f32m);
#pragma unroll
        for (int mi = 0; mi < 2; ++mi) {
            int rb = mi * 16 + (lane >> 4) * 4;
#pragma unroll
            for (int r = 0; r < 4; ++r) {
                float v = acc[mi][ni][r] + b;
                if (doGelu) v = gelu_f(v);
                hl[(rb + r) * XS + col] = f2bf(v);
            }
        }
    }
}

// epilogue with gathered-partial add: v = gelu(acc + g + bias)
__device__ __forceinline__ void epi_gadd(f32x4 acc[2][2], const float g[2][2][4], u16* hl,
                                         const void* biasG, int wave, int lane, int f32m) {
    int col0 = wave * 32;
#pragma unroll
    for (int ni = 0; ni < 2; ++ni) {
        int col = col0 + ni * 16 + (lane & 15);
        float b = ldv(biasG, col, f32m);
#pragma unroll
        for (int mi = 0; mi < 2; ++mi) {
            int rb = mi * 16 + (lane >> 4) * 4;
#pragma unroll
            for (int r = 0; r < 4; ++r)
                hl[(rb + r) * XS + col] = f2bf(gelu_f(acc[mi][ni][r] + g[mi][ni][r] + b));
        }
    }
}

// stage 8 contiguous elems (col c8*8) of row `row` of a 128-wide table into LDS
__device__ __forceinline__ void stage_row8(u16* dst8, const void* table, size_t row, int c8, int f32m) {
    if (f32m) {
        const float* s = (const float*)table + row * 128 + c8 * 8;
        float4 v0 = *(const float4*)s;
        float4 v1 = *(const float4*)(s + 4);
        uint4 o;
        o.x = (u32)f2bf(v0.x) | ((u32)f2bf(v0.y) << 16);
        o.y = (u32)f2bf(v0.z) | ((u32)f2bf(v0.w) << 16);
        o.z = (u32)f2bf(v1.x) | ((u32)f2bf(v1.y) << 16);
        o.w = (u32)f2bf(v1.z) | ((u32)f2bf(v1.w) << 16);
        *(uint4*)dst8 = o;
    } else {
        *(uint4*)dst8 = *(const uint4*)((const u16*)table + row * 128 + c8 * 8);
    }
}

__device__ __forceinline__ void stage_seq(u16* dst, const void* table, size_t rowBase, int tid, int f32m) {
    int r0 = tid >> 4, c = tid & 15;
#pragma unroll
    for (int p = 0; p < 2; ++p) {
        int r = r0 + p * 16;
        stage_row8(&dst[r * XS + c * 8], table, rowBase + r, c, f32m);
    }
}

// ---------------- dtype detector ----------------
__global__ void k_detect(const void* hV, int* flag) {
    int l = threadIdx.x;
    const u16* p = (const u16*)hV;
    float m = fmaxf(fabsf(bf2f(p[l])), fabsf(bf2f(p[64 + l])));
    for (int s = 1; s < 64; s <<= 1) m = fmaxf(m, __shfl_xor(m, s));
    if (l == 0) *flag = (m > 1e4f) ? 1 : 0;
}

// ---------------- kernel: pack weights into B-fragment order ----------------
__global__ void k_pack(const void* bb1, const void* bb2, const void* wv1, const void* wv2,
                       const void* wv3, const void* wo, const void* d1, const void* d2,
                       const void* e1, const void* e2, const void* e3, const void* bb3,
                       u16* pw, const int* dflag) {
    int f32m = *dflag;
    const int Ks[12] = {384, 128, 256, 128, 128, 128, 128, 512, 384, 128, 128, 128};
    const int Ns[12] = {128, 128, 128, 128, 128, 128, 512, 128, 128, 128, 128, 16};
    const void* srcs[12] = {bb1, bb2, wv1, wv2, wv3, wo, d1, d2, e1, e2, e3, bb3};
    int gid = blockIdx.x * 256 + threadIdx.x;
    int lane = gid & 63;
    int fid = gid >> 6;
    if (fid >= 708) return;
    int w = 0, base = 0, dstoff = 0;
    for (int i = 0; i < 12; ++i) {
        int nf = (Ks[i] / 32) * (Ns[i] / 16);
        if (fid < base + nf) { w = i; break; }
        base += nf;
        dstoff += Ks[i] * Ns[i];
    }
    int f = fid - base;
    int N = Ns[w];
    int kc = f / (N / 16), nc = f % (N / 16);
    const void* S = srcs[w];
    u16* D = pw + dstoff + ((size_t)f * 64 + lane) * 8;
    int krow = kc * 32 + (lane >> 4) * 8;
    int col = nc * 16 + (lane & 15);
#pragma unroll
    for (int j = 0; j < 8; ++j) {
        float v;
        if (w == 11) v = (col < 4) ? ldv(S, (size_t)(krow + j) * 4 + col, f32m) : 0.f;
        else         v = ldv(S, (size_t)(krow + j) * N + col, f32m);
        D[j] = f2bf(v);
    }
}

// ---------------- CSR build ----------------
__global__ void k_hist(const int* src, int* hist) {
    int e = blockIdx.x * 256 + threadIdx.x;
    if (e < NE) atomicAdd(&hist[src[e]], 1);
}

__global__ void k_scan(const int* hist, int* offs, int* cnt) {
    __shared__ int buf[1024];
    __shared__ int carry;
    if (threadIdx.x == 0) carry = 0;
    __syncthreads();
    for (int b = 0; b < NN; b += 1024) {
        int i = b + threadIdx.x;
        int v = (i < NN) ? hist[i] : 0;
        buf[threadIdx.x] = v;
        __syncthreads();
        for (int s = 1; s < 1024; s <<= 1) {
            int t = (threadIdx.x >= s) ? buf[threadIdx.x - s] : 0;
            __syncthreads();
            buf[threadIdx.x] += t;
            __syncthreads();
        }
        int excl = buf[threadIdx.x] - v + carry;
        if (i < NN) { offs[i] = excl; cnt[i] = excl; }
        __syncthreads();
        if (threadIdx.x == 1023) carry += buf[1023];
        __syncthreads();
    }
    if (threadIdx.x == 0) offs[NN] = carry;
}

__global__ void k_fill(const int* src, int* cnt, int* eids) {
    int e = blockIdx.x * 256 + threadIdx.x;
    if (e < NE) {
        int slot = atomicAdd(&cnt[src[e]], 1);
        eids[slot] = e;
    }
}

// ---------------- kernel: per-node precompute for edge layer-1 (attention) ----------------
// PA = hV @ BB1[0:128,:], PC = hV @ BB1[256:384,:], PV = hV @ WV1[128:256,:]   (all f32 out)
__global__ __launch_bounds__(256, 2) void k_pre1(
    const void* __restrict__ hV, const u16* __restrict__ pw,
    float* __restrict__ pa, float* __restrict__ pc,
    void* __restrict__ dout, float* __restrict__ pvws, const int* dflag) {
    __shared__ __attribute__((aligned(16))) u16 xb[TM * XS];
    int f32m = *dflag;
    float* pv = f32m ? (float*)((char*)dout + (size_t)NN * 512 + (size_t)NE * 256) : pvws;
    int tid = threadIdx.x, wave = tid >> 6, lane = tid & 63;
    long n0 = (long)blockIdx.x * TM;   // 625 blocks x 32 = 20000 exactly
    stage_seq(xb, hV, (size_t)n0, tid, f32m);
    __syncthreads();
    f32x4 aA[2][2] = {}, aC[2][2] = {}, aV[2][2] = {};
    mma128(xb, pw + PK_BB1, 0, 8, wave, lane, aA);   // BB1 rows 0-127 (src part)
    mma128(xb, pw + PK_BB1, 8, 8, wave, lane, aC);   // BB1 rows 256-383 (dst part)
    mma128(xb, pw + PK_WV1, 4, 8, wave, lane, aV);   // WV1 rows 128-255 (dst part)
    int col0 = wave * 32, rbase = (lane >> 4) * 4, cl = lane & 15;
#pragma unroll
    for (int ni = 0; ni < 2; ++ni) {
        int col = col0 + ni * 16 + cl;
#pragma unroll
        for (int mi = 0; mi < 2; ++mi)
#pragma unroll
            for (int r = 0; r < 4; ++r) {
                size_t row = (size_t)(n0 + mi * 16 + rbase + r);
                pa[row * 128 + col] = aA[mi][ni][r];
                pc[row * 128 + col] = aC[mi][ni][r];
                pv[row * 128 + col] = aV[mi][ni][r];
            }
    }
}

// ---------------- kernel: per-node precompute for edge MLP (E1 src/dst parts) ----------------
__global__ __launch_bounds__(256, 2) void k_pre2(
    const void* __restrict__ hV2, const u16* __restrict__ pw,
    float* __restrict__ p2a, float* __restrict__ p2c, const int* dflag) {
    __shared__ __attribute__((aligned(16))) u16 xb[TM * XS];
    int f32m = *dflag;
    int tid = threadIdx.x, wave = tid >> 6, lane = tid & 63;
    long n0 = (long)blockIdx.x * TM;
    stage_seq(xb, hV2, (size_t)n0, tid, f32m);
    __syncthreads();
    f32x4 aA[2][2] = {}, aC[2][2] = {};
    mma128(xb, pw + PK_E1, 0, 8, wave, lane, aA);    // E1 rows 0-127 (src part)
    mma128(xb, pw + PK_E1, 8, 8, wave, lane, aC);    // E1 rows 256-383 (dst part)
    int col0 = wave * 32, rbase = (lane >> 4) * 4, cl = lane & 15;
#pragma unroll
    for (int ni = 0; ni < 2; ++ni) {
        int col = col0 + ni * 16 + cl;
#pragma unroll
        for (int mi = 0; mi < 2; ++mi)
#pragma unroll
            for (int r = 0; r < 4; ++r) {
                size_t row = (size_t)(n0 + mi * 16 + rbase + r);
                p2a[row * 128 + col] = aA[mi][ni][r];
                p2c[row * 128 + col] = aC[mi][ni][r];
            }
    }
}

// ---------------- kernel: fused bias-MLP + value-MLP over edges ----------------
// Layer-1 src/dst contributions come from per-node precomputed tables (register gathers);
// only hE is staged (coalesced). 4 barriers.
__global__ __launch_bounds__(256, 2) void k_edge1(
    const void* __restrict__ hE, const int* __restrict__ eidx,
    const u16* __restrict__ pw,
    const float* __restrict__ pa, const float* __restrict__ pc,
    const void* bb1b, const void* bb2b, const void* bb3b,
    const void* wv1b, const void* wv2b, const void* wv3b,
    float* __restrict__ wlog, void* __restrict__ dout,
    const float* __restrict__ pvws, const int* dflag) {
    __shared__ __attribute__((aligned(16))) u16 X[TM * XS];
    __shared__ __attribute__((aligned(16))) u16 Y[TM * XS];
    __shared__ __attribute__((aligned(16))) u16 Z[TM * XS];
    int f32m = *dflag;
    const float* pv = f32m ? (const float*)((const char*)dout + (size_t)NN * 512 + (size_t)NE * 256)
                           : pvws;
    int tid = threadIdx.x, wave = tid >> 6, lane = tid & 63;
    long e0 = (long)blockIdx.x * TM;

    // P1: stage hE -> Y (coalesced); gather precomputed layer-1 partials into regs
    stage_seq(Y, hE, (size_t)e0, tid, f32m);
    int col0 = wave * 32, rbase = (lane >> 4) * 4, cl = lane & 15;
    float gB[2][2][4], gV[2][2][4];
#pragma unroll
    for (int mi = 0; mi < 2; ++mi)
#pragma unroll
        for (int r = 0; r < 4; ++r) {
            long row = e0 + mi * 16 + rbase + r;
            size_t s = (size_t)eidx[row];
            size_t d = (size_t)eidx[NE + row];
#pragma unroll
            for (int ni = 0; ni < 2; ++ni) {
                int col = col0 + ni * 16 + cl;
                gB[mi][ni][r] = pa[s * 128 + col] + pc[d * 128 + col];
                gV[mi][ni][r] = pv[d * 128 + col];
            }
        }
    __syncthreads();
    // P2: hE chunks of layer 1; epilogues (with gathered partials) into fresh X, Z
    f32x4 accB[2][2] = {};
    f32x4 accV[2][2] = {};
    mma128(Y, pw + PK_BB1, 4, 8, wave, lane, accB);   // BB1 rows 128-255 (hE part)
    mma128(Y, pw + PK_WV1, 0, 8, wave, lane, accV);   // WV1 rows 0-127 (hE part)
    epi_gadd(accB, gB, X, bb1b, wave, lane, f32m);    // h1b -> X
    epi_gadd(accV, gV, Z, wv1b, wave, lane, f32m);    // h1v -> Z
    __syncthreads();
    // P3: layer-2 MFMAs; h2b epilogue into freed Y
    f32x4 accB2[2][2] = {};
    f32x4 accV2[2][2] = {};
    mma128(X, pw + PK_BB2, 0, 8, wave, lane, accB2);
    mma128(Z, pw + PK_WV2, 0, 8, wave, lane, accV2);
    epi_lds(accB2, Y, bb2b, wave, lane, true, f32m);  // h2b -> Y
    __syncthreads();
    // P4: h2v epilogue into freed X
    epi_lds(accV2, X, wv2b, wave, lane, true, f32m);  // h2v -> X
    __syncthreads();
    // P5: l3 value (WV3 on X) -> Vout; l3 bias (BB3 on Y, wave 0) -> wlog
    u16* Vout = (u16*)((char*)dout + (size_t)NN * 128 * (f32m ? 4 : 2));
    f32x4 accV3[2][2] = {};
    mma128(X, pw + PK_WV3, 0, 8, wave, lane, accV3);
    {
#pragma unroll
        for (int ni = 0; ni < 2; ++ni) {
            int col = col0 + ni * 16 + cl;
            float b = ldv(wv3b, col, f32m);
#pragma unroll
            for (int mi = 0; mi < 2; ++mi) {
                int rb = mi * 16 + rbase;
#pragma unroll
                for (int r = 0; r < 4; ++r) {
                    long row = e0 + rb + r;
                    Vout[row * 128 + col] = f2bf(accV3[mi][ni][r] + b);
                }
            }
        }
    }
    if (wave == 0) {
        f32x4 aw0 = {0.f, 0.f, 0.f, 0.f};
        f32x4 aw1 = {0.f, 0.f, 0.f, 0.f};
#pragma unroll
        for (int kc = 0; kc < 4; ++kc) {
            int koff = kc * 32 + (lane >> 4) * 8;
            bf16x8 a0 = *(const bf16x8*)&Y[(lane & 15) * XS + koff];
            bf16x8 a1 = *(const bf16x8*)&Y[((lane & 15) + 16) * XS + koff];
            bf16x8 b = *(const bf16x8*)&pw[PK_BB3 + ((size_t)kc * 64 + lane) * 8];
            aw0 = MFMA(a0, b, aw0);
            aw1 = MFMA(a1, b, aw1);
        }
        if ((lane & 15) < 4) {
            int col = lane & 15;
            float b3 = ldv(bb3b, col, f32m);
#pragma unroll
            for (int r = 0; r < 4; ++r) {
                wlog[(e0 + rbase + r) * 4 + col] = aw0[r] + b3;
                wlog[(e0 + 16 + rbase + r) * 4 + col] = aw1[r] + b3;
            }
        }
    }
}

// ---------------- kernel: per-node scatter-softmax + weighted segment sum ----------------
__global__ void k_agg(const int* __restrict__ offs, const int* __restrict__ eids,
                      const float* __restrict__ wlog, const void* __restrict__ dout,
                      float* __restrict__ agg, const int* dflag) {
    int f32m = *dflag;
    const u16* V = (const u16*)((const char*)dout + (size_t)NN * 128 * (f32m ? 4 : 2));
    int node = blockIdx.x;
    int l = threadIdx.x;   // 0..63
    int beg = offs[node], end = offs[node + 1];
    int deg = end - beg;
    if (deg == 0) {
        agg[(size_t)node * 128 + 2 * l] = 0.f;
        agg[(size_t)node * 128 + 2 * l + 1] = 0.f;
        return;
    }
    int h = l & 3;
    float lmax = -3.0e38f;
    for (int i = (l >> 2); i < deg; i += 16) {
        int e = eids[beg + i];
        lmax = fmaxf(lmax, wlog[(size_t)e * 4 + h]);
    }
    for (int s = 4; s < 64; s <<= 1) lmax = fmaxf(lmax, __shfl_xor(lmax, s));
    float lsum = 0.f;
    for (int i = (l >> 2); i < deg; i += 16) {
        int e = eids[beg + i];
        lsum += __expf(wlog[(size_t)e * 4 + h] - lmax);
    }
    for (int s = 4; s < 64; s <<= 1) lsum += __shfl_xor(lsum, s);
    int hh = l >> 4;                // head of cols (2l, 2l+1)
    float mh = __shfl(lmax, hh);
    float inv = __builtin_amdgcn_rcpf(__shfl(lsum, hh));
    float a0 = 0.f, a1 = 0.f;
    for (int i = 0; i < deg; ++i) {
        int e = eids[beg + i];
        float aw = __expf(wlog[(size_t)e * 4 + hh] - mh) * inv;
        u32 vv = *(const u32*)&V[(size_t)e * 128 + 2 * l];
        a0 += aw * bf2f((u16)(vv & 0xffffu));
        a1 += aw * bf2f((u16)(vv >> 16));
    }
    float2 o;
    o.x = a0;
    o.y = a1;
    *(float2*)&agg[(size_t)node * 128 + 2 * l] = o;
}

// ---------------- kernel: dh = agg @ wo ; r0 = hV + dh ; BN0 stats ----------------
__global__ __launch_bounds__(256, 2) void k_wo(const float* __restrict__ agg,
                                               const void* __restrict__ hV,
                                               const u16* __restrict__ pw,
                                               float* __restrict__ rbuf,
                                               float* __restrict__ stats0, const int* dflag) {
    __shared__ __attribute__((aligned(16))) u16 xb[TM * XS];
    __shared__ float lsum[128], lsq[128];
    int f32m = *dflag;
    int tid = threadIdx.x, wave = tid >> 6, lane = tid & 63;
    long n0 = (long)blockIdx.x * TM;
    if (tid < 128) { lsum[tid] = 0.f; lsq[tid] = 0.f; }
    {
        int r = tid >> 3, cc = (tid & 7) * 16;
        long row = n0 + r;
        for (int j = 0; j < 16; j += 4) {
            float4 v = {0.f, 0.f, 0.f, 0.f};
            if (row < NN) v = *(const float4*)&agg[row * 128 + cc + j];
            u16* d = &xb[r * XS + cc + j];
            d[0] = f2bf(v.x); d[1] = f2bf(v.y); d[2] = f2bf(v.z); d[3] = f2bf(v.w);
        }
    }
    __syncthreads();
    f32x4 acc[2][2] = {};
    mma128(xb, pw + PK_WO, 0, 8, wave, lane, acc);
    int col0 = wave * 32;
#pragma unroll
    for (int ni = 0; ni < 2; ++ni) {
        int col = col0 + ni * 16 + (lane & 15);
#pragma unroll
        for (int mi = 0; mi < 2; ++mi) {
            int rb = mi * 16 + (lane >> 4) * 4;
#pragma unroll
            for (int r = 0; r < 4; ++r) {
                long row = n0 + rb + r;
                if (row < NN) {
                    float v = ldv(hV, (size_t)row * 128 + col, f32m) + acc[mi][ni][r];
                    rbuf[row * 128 + col] = v;
                    atomicAdd(&lsum[col], v);
                    atomicAdd(&lsq[col], v * v);
                }
            }
        }
    }
    __syncthreads();
    if (tid < 128) {
        atomicAdd(&stats0[tid], lsum[tid]);
        atomicAdd(&stats0[128 + tid], lsq[tid]);
    }
}

// ---------------- kernel: BN0 apply + FFN + residual + BN1 stats ----------------
__global__ __launch_bounds__(256, 2) void k_ffn(float* __restrict__ rbuf,
                                                const float* __restrict__ stats0,
                                                const void* n0g, const void* n0b,
                                                const u16* __restrict__ pw,
                                                const void* d1b, const void* d2b,
                                                float* __restrict__ stats1, const int* dflag) {
    __shared__ float bnS[128], bnB[128];
    __shared__ float h1f[TM * 128];
    __shared__ __attribute__((aligned(16))) u16 h1x[TM * XS];
    __shared__ __attribute__((aligned(16))) u16 hid[TM * 520];
    __shared__ float lsum[128], lsq[128];
    int f32m = *dflag;
    int tid = threadIdx.x, wave = tid >> 6, lane = tid & 63;
    long n0 = (long)blockIdx.x * TM;
    if (tid < 128) {
        float m = stats0[tid] * (1.f / NN);
        float v = stats0[128 + tid] * (1.f / NN) - m * m;
        float s = ldv(n0g, tid, f32m) * rsqrtf(v + 1e-5f);
        bnS[tid] = s;
        bnB[tid] = ldv(n0b, tid, f32m) - m * s;
        lsum[tid] = 0.f;
        lsq[tid] = 0.f;
    }
    __syncthreads();
    {
        int r = tid >> 3, cc = (tid & 7) * 16;
        long row = n0 + r;
        for (int j = 0; j < 16; ++j) {
            int c = cc + j;
            float v = (row < NN) ? (rbuf[row * 128 + c] * bnS[c] + bnB[c]) : 0.f;
            h1f[r * 128 + c] = v;
            h1x[r * XS + c] = f2bf(v);
        }
    }
    __syncthreads();
    // GEMM1: (32 x 128) @ (128 x 512)
    f32x4 acc1[2][8] = {};
#pragma unroll
    for (int kc = 0; kc < 4; ++kc) {
        int koff = kc * 32 + (lane >> 4) * 8;
        bf16x8 a0 = *(const bf16x8*)&h1x[(lane & 15) * XS + koff];
        bf16x8 a1 = *(const bf16x8*)&h1x[((lane & 15) + 16) * XS + koff];
#pragma unroll
        for (int ni = 0; ni < 8; ++ni) {
            int nc = wave * 8 + ni;
            bf16x8 b = *(const bf16x8*)&pw[PK_D1 + (((size_t)kc * 32 + nc) * 64 + lane) * 8];
            acc1[0][ni] = MFMA(a0, b, acc1[0][ni]);
            acc1[1][ni] = MFMA(a1, b, acc1[1][ni]);
        }
    }
#pragma unroll
    for (int ni = 0; ni < 8; ++ni) {
        int col = wave * 128 + ni * 16 + (lane & 15);
        float bb = ldv(d1b, col, f32m);
#pragma unroll
        for (int mi = 0; mi < 2; ++mi) {
            int rb = mi * 16 + (lane >> 4) * 4;
#pragma unroll
            for (int r = 0; r < 4; ++r)
                hid[(rb + r) * 520 + col] = f2bf(gelu_f(acc1[mi][ni][r] + bb));
        }
    }
    __syncthreads();
    // GEMM2: (32 x 512) @ (512 x 128)
    f32x4 acc2[2][2] = {};
#pragma unroll
    for (int kc = 0; kc < 16; ++kc) {
        int koff = kc * 32 + (lane >> 4) * 8;
        bf16x8 a0 = *(const bf16x8*)&hid[(lane & 15) * 520 + koff];
        bf16x8 a1 = *(const bf16x8*)&hid[((lane & 15) + 16) * 520 + koff];
#pragma unroll
        for (int ni = 0; ni < 2; ++ni) {
            int nc = wave * 2 + ni;
            bf16x8 b = *(const bf16x8*)&pw[PK_D2 + (((size_t)kc * 8 + nc) * 64 + lane) * 8];
            acc2[0][ni] = MFMA(a0, b, acc2[0][ni]);
            acc2[1][ni] = MFMA(a1, b, acc2[1][ni]);
        }
    }
    int col0 = wave * 32;
#pragma unroll
    for (int ni = 0; ni < 2; ++ni) {
        int col = col0 + ni * 16 + (lane & 15);
        float db = ldv(d2b, col, f32m);
#pragma unroll
        for (int mi = 0; mi < 2; ++mi) {
            int rb = mi * 16 + (lane >> 4) * 4;
#pragma unroll
            for (int r = 0; r < 4; ++r) {
                long row = n0 + rb + r;
                if (row < NN) {
                    float v = h1f[(rb + r) * 128 + col] + acc2[mi][ni][r] + db;
                    rbuf[row * 128 + col] = v;
                    atomicAdd(&lsum[col], v);
                    atomicAdd(&lsq[col], v * v);
                }
            }
        }
    }
    __syncthreads();
    if (tid < 128) {
        atomicAdd(&stats1[tid], lsum[tid]);
        atomicAdd(&stats1[128 + tid], lsq[tid]);
    }
}

// ---------------- kernel: BN1 normalize -> h_V output ----------------
__global__ void k_out_hV(const float* __restrict__ rbuf, const float* __restrict__ stats1,
                         const void* n1g, const void* n1b, void* __restrict__ dout,
                         const int* dflag) {
    int f32m = *dflag;
    int idx = blockIdx.x * 256 + threadIdx.x;
    if (idx >= NN * 128) return;
    int c = idx & 127;
    float m = stats1[c] * (1.f / NN);
    float v = stats1[128 + c] * (1.f / NN) - m * m;
    float s = ldv(n1g, c, f32m) * rsqrtf(v + 1e-5f);
    float b = ldv(n1b, c, f32m) - m * s;
    float o = rbuf[idx] * s + b;
    if (f32m) ((float*)dout)[idx] = o;
    else      ((u16*)dout)[idx] = f2bf(o);
}

// ---------------- kernel: edge MLP + residual + edge-BN stats ----------------
// E1 src/dst parts from per-node tables; only hE staged. 2 LDS buffers, 3 barriers.
__global__ __launch_bounds__(256, 2) void k_edge2(
    const void* __restrict__ hE, const int* __restrict__ eidx,
    const u16* __restrict__ pw,
    const float* __restrict__ p2a, const float* __restrict__ p2c,
    const void* e1b, const void* e2b, const void* e3b,
    void* __restrict__ dout, float* __restrict__ statsE, const int* dflag) {
    __shared__ __attribute__((aligned(16))) u16 X[TM * XS];
    __shared__ __attribute__((aligned(16))) u16 Y[TM * XS];
    int f32m = *dflag;
    int tid = threadIdx.x, wave = tid >> 6, lane = tid & 63;
    long e0 = (long)blockIdx.x * TM;

    // P1: stage hE -> X; gather E1 src/dst partials; preload residual
    stage_seq(X, hE, (size_t)e0, tid, f32m);
    int col0 = wave * 32, rbase = (lane >> 4) * 4, cl = lane & 15;
    float g1[2][2][4], res[2][2][4];
#pragma unroll
    for (int mi = 0; mi < 2; ++mi)
#pragma unroll
        for (int r = 0; r < 4; ++r) {
            long row = e0 + mi * 16 + rbase + r;
            size_t s = (size_t)eidx[row];
            size_t d = (size_t)eidx[NE + row];
#pragma unroll
            for (int ni = 0; ni < 2; ++ni) {
                int col = col0 + ni * 16 + cl;
                g1[mi][ni][r] = p2a[s * 128 + col] + p2c[d * 128 + col];
                res[mi][ni][r] = ldv(hE, (size_t)row * 128 + col, f32m);
            }
        }
    __syncthreads();
    // P2: E1 hE chunk; epi (with gathered partials) -> Y
    f32x4 a1[2][2] = {};
    mma128(X, pw + PK_E1, 4, 8, wave, lane, a1);      // E1 rows 128-255 (hE part)
    epi_gadd(a1, g1, Y, e1b, wave, lane, f32m);       // h1 -> Y
    __syncthreads();
    // P3: E2 + epi -> X (hE dead)
    f32x4 a2[2][2] = {};
    mma128(Y, pw + PK_E2, 0, 8, wave, lane, a2);
    epi_lds(a2, X, e2b, wave, lane, true, f32m);      // h2 -> X
    __syncthreads();
    // P4: E3 + epilogue (residual from preloaded regs)
    f32x4 a3[2][2] = {};
    mma128(X, pw + PK_E3, 0, 8, wave, lane, a3);
    float* yb32 = (float*)((char*)dout + (size_t)NN * 512);
    u16*   yb16 = (u16*)((char*)dout + (size_t)NN * 256);
    float ssum[2] = {0.f, 0.f}, ssq[2] = {0.f, 0.f};
#pragma unroll
    for (int ni = 0; ni < 2; ++ni) {
        int col = col0 + ni * 16 + cl;
        float b = ldv(e3b, col, f32m);
#pragma unroll
        for (int mi = 0; mi < 2; ++mi) {
            int rb = mi * 16 + rbase;
#pragma unroll
            for (int r = 0; r < 4; ++r) {
                long row = e0 + rb + r;
                float y = res[mi][ni][r] + a3[mi][ni][r] + b;
                if (f32m) yb32[row * 128 + col] = y;
                else      yb16[row * 128 + col] = f2bf(y);
                ssum[ni] += y;
                ssq[ni] += y * y;
            }
        }
    }
    // lanes {c, c+16, c+32, c+48} together cover all 32 rows of column col0+ni*16+c
#pragma unroll
    for (int ni = 0; ni < 2; ++ni) {
        ssum[ni] += __shfl_xor(ssum[ni], 16);
        ssum[ni] += __shfl_xor(ssum[ni], 32);
        ssq[ni]  += __shfl_xor(ssq[ni], 16);
        ssq[ni]  += __shfl_xor(ssq[ni], 32);
    }
    if (lane < 16) {
#pragma unroll
        for (int ni = 0; ni < 2; ++ni) {
            int col = col0 + ni * 16 + lane;
            atomicAdd(&statsE[col], ssum[ni]);
            atomicAdd(&statsE[128 + col], ssq[ni]);
        }
    }
}

// ---------------- kernel: edge BN normalize in place -> h_E output (vec4) ----------------
__global__ void k_out_hE(const float* __restrict__ statsE, const void* eng, const void* enb,
                         void* __restrict__ dout, const int* dflag) {
    int f32m = *dflag;
    long i4 = (long)blockIdx.x * 256 + threadIdx.x;   // 4-elem group
    if (i4 >= (long)NE * 32) return;
    int c0 = (int)((i4 & 31) * 4);
    float s[4], b[4];
#pragma unroll
    for (int j = 0; j < 4; ++j) {
        int c = c0 + j;
        float m = statsE[c] * (1.f / NE);
        float v = statsE[128 + c] * (1.f / NE) - m * m;
        float sc = ldv(eng, c, f32m) * rsqrtf(v + 1e-5f);
        s[j] = sc;
        b[j] = ldv(enb, c, f32m) - m * sc;
    }
    if (f32m) {
        float4* y = (float4*)((char*)dout + (size_t)NN * 512);
        float4 v = y[i4];
        v.x = v.x * s[0] + b[0];
        v.y = v.y * s[1] + b[1];
        v.z = v.z * s[2] + b[2];
        v.w = v.w * s[3] + b[3];
        y[i4] = v;
    } else {
        ushort4* y = (ushort4*)((char*)dout + (size_t)NN * 256);
        ushort4 v = y[i4];
        v.x = f2bf(bf2f(v.x) * s[0] + b[0]);
        v.y = f2bf(bf2f(v.y) * s[1] + b[1]);
        v.z = f2bf(bf2f(v.z) * s[2] + b[2]);
        v.w = f2bf(bf2f(v.w) * s[3] + b[3]);
        y[i4] = v;
    }
}

// ---------------- launch ----------------
extern "C" void kernel_launch(void* const* d_in, const int* in_sizes, int n_in,
                              void* d_out, int out_size, void* d_ws, size_t ws_size,
                              hipStream_t stream) {
    (void)in_sizes; (void)n_in; (void)out_size; (void)ws_size;
    const void* hV = d_in[0];
    const void* hE = d_in[1];
    const int* eidx = (const int*)d_in[2];
    // d_in[3] batch_id unused (context is identity)
    const void* wv1w = d_in[4];  const void* wv1b = d_in[5];
    const void* wv2w = d_in[6];  const void* wv2b = d_in[7];
    const void* wv3w = d_in[8];  const void* wv3b = d_in[9];
    const void* bb1w = d_in[10]; const void* bb1b = d_in[11];
    const void* bb2w = d_in[12]; const void* bb2b = d_in[13];
    const void* bb3w = d_in[14]; const void* bb3b = d_in[15];
    const void* wow  = d_in[16];
    const void* n0g = d_in[17]; const void* n0b = d_in[18];
    const void* n1g = d_in[19]; const void* n1b = d_in[20];
    const void* d1w = d_in[21]; const void* d1b = d_in[22];
    const void* d2w = d_in[23]; const void* d2b = d_in[24];
    const void* e1w = d_in[25]; const void* e1b = d_in[26];
    const void* e2w = d_in[27]; const void* e2b = d_in[28];
    const void* e3w = d_in[29]; const void* e3b = d_in[30];
    const void* eng = d_in[31]; const void* enb = d_in[32];

    char* ws = (char*)d_ws;
    u16* pw      = (u16*)(ws + WS_PW);
    float* stats = (float*)(ws + WS_STATS);   // stats0 | stats1(+256) | statsE(+512)
    int* dflag   = (int*)(ws + WS_FLAG);
    int* hist    = (int*)(ws + WS_HIST);
    int* offs    = (int*)(ws + WS_OFFS);
    int* cnt     = (int*)(ws + WS_CNT);
    int* eids    = (int*)(ws + WS_EIDS);
    float* wlog  = (float*)(ws + WS_WLOG);
    float* agg   = (float*)(ws + WS_AGG);     // doubles as PA (k_pre1/k_edge1) and P2a (k_pre2/k_edge2)
    float* rbuf  = (float*)(ws + WS_R);       // doubles as PC and P2c
    float* pvws  = (float*)(ws + WS_PV);      // PV backing store (bf16-input mode only)

    // zero stats/flag (4KB) + hist (80000B), contiguous
    hipMemsetAsync(ws + WS_STATS, 0, 0x1000 + NN * sizeof(int), stream);

    k_detect<<<1, 64, 0, stream>>>(hV, dflag);
    k_pack<<<177, 256, 0, stream>>>(bb1w, bb2w, wv1w, wv2w, wv3w, wow, d1w, d2w,
                                    e1w, e2w, e3w, bb3w, pw, dflag);
    k_hist<<<(NE + 255) / 256, 256, 0, stream>>>(eidx, hist);
    k_scan<<<1, 1024, 0, stream>>>(hist, offs, cnt);
    k_fill<<<(NE + 255) / 256, 256, 0, stream>>>(eidx, cnt, eids);
    // per-node precompute for attention layer-1 (PA -> agg region, PC -> rbuf region, PV -> d_out slack/ws)
    k_pre1<<<NN / TM, 256, 0, stream>>>(hV, pw, agg, rbuf, d_out, pvws, dflag);
    k_edge1<<<NE / TM, 256, 0, stream>>>(hE, eidx, pw, agg, rbuf, bb1b, bb2b, bb3b,
                                         wv1b, wv2b, wv3b, wlog, d_out, pvws, dflag);
    k_agg<<<NN, 64, 0, stream>>>(offs, eids, wlog, d_out, agg, dflag);
    k_wo<<<(NN + TM - 1) / TM, 256, 0, stream>>>(agg, hV, pw, rbuf, stats, dflag);
    k_ffn<<<(NN + TM - 1) / TM, 256, 0, stream>>>(rbuf, stats, n0g, n0b, pw, d1b, d2b,
                                                  stats + 256, dflag);
    k_out_hV<<<(NN * 128 + 255) / 256, 256, 0, stream>>>(rbuf, stats + 256, n1g, n1b, d_out, dflag);
    // per-node precompute for edge-MLP E1 (P2a -> agg region, P2c -> rbuf region; both dead now)
    k_pre2<<<NN / TM, 256, 0, stream>>>(d_out, pw, agg, rbuf, dflag);
    k_edge2<<<NE / TM, 256, 0, stream>>>(hE, eidx, pw, agg, rbuf, e1b, e2b, e3b,
                                         d_out, stats + 512, dflag);
    k_out_hE<<<(int)(((long)NE * 32 + 255) / 256), 256, 0, stream>>>(stats + 512, eng, enb, d_out, dflag);
}